// Round 8
// baseline (183.877 us; speedup 1.0000x reference)
//
#include <hip/hip_runtime.h>
#include <math.h>

// SemiConnectedConv as dense bf16-MFMA implicit GEMM, 3 kernels.
// Round-8: main uses mfma_f32_32x32x16_bf16 (K=16 = one tap x 16ch, one wave
// = 32px x ALL 32 branches), 4 output rows per block, XOR-swizzled 16B units.
//  1) prep_wfrag32: weights -> B-frags short[26 tap][64 lane][8]  (26.6 KB ws)
//     B layout (32x32x16): col n = lane&31, k(=channel) = (lane>>5)*8 + j
//  2) transpose_x:  fp32 NCHW -> bf16 swizzled-NHWC xT[b][228 row][456 unit*8]
//     unit(pcol, chalf) = pcol*2 + (chalf ^ ((pcol>>2)&1))   (16B units)
//  3) semiconv_main: block = (batch, 4 output rows): stage 8 contiguous xT
//     rows (58.4 KB) via global_load_lds (linear copy preserves swizzle),
//     26-tap x 4-row MFMA, sigmoid + float4 stores.
// A layout (32x32x16): row(px) = lane&31, k(=ch) = (lane>>5)*8 + j
// D layout (m74/m101): col(branch) = lane&31, row(px) = (reg&3)+8*(reg>>2)+4*(lane>>5)

#define HH 224
#define WW 224
#define BB 16
#define CIN 16
#define NBR 32
#define PH 228
#define PW 228
#define HW (HH * WW)
#define UNITS 456                 // 16B units per padded row = 228 px * 2 halves

typedef short short8 __attribute__((ext_vector_type(8)));
typedef float f32x16 __attribute__((ext_vector_type(16)));

static __device__ __forceinline__ unsigned short f2bf(float f) {
    unsigned int u = __float_as_uint(f);
    return (unsigned short)((u + 0x7FFFu + ((u >> 16) & 1u)) >> 16);   // RNE
}

// ---- weights -> B-fragments: short bfrag[26][64][8] ----
__global__ __launch_bounds__(64)
void prep_wfrag32(const float* __restrict__ Wc, short* __restrict__ ws) {
    const int tap = blockIdx.x;               // 0..25
    const int lane = threadIdx.x;
    const int n = lane & 31;                  // branch
    const int cgrp = lane >> 5;
    short8 pack;
    #pragma unroll
    for (int j = 0; j < 8; ++j) {
        int c = cgrp * 8 + j;
        float val = 0.0f;
        if (tap < 25 && (((c + n) & 15) < 8)) {
            int jsel = 0;
            for (int cc = 0; cc < c; ++cc) jsel += (((cc + n) & 15) < 8) ? 1 : 0;
            val = Wc[(n * 8 + jsel) * 25 + tap];
        }
        pack[j] = (short)f2bf(val);
    }
    *(short8*)(ws + (size_t)(tap * 64 + lane) * 8) = pack;
}

// ---- x fp32 NCHW -> xT bf16 swizzled rows; 4 rows/block, 2-thread ch split --
__global__ __launch_bounds__(512)
void transpose_x(const float* __restrict__ x, short* __restrict__ xT) {
    const int b = blockIdx.y;
    const int prow = blockIdx.x * 4 + (threadIdx.x >> 7);   // 0..227
    const int u = threadIdx.x & 127;
    const int gh = prow - 2;
    const bool rok = (unsigned)gh < (unsigned)HH;
    short* dst = xT + ((size_t)b * PH + prow) * (UNITS * 8);

    if (u < 112) {
        const int t4 = u >> 1;                // 0..55
        const int sh8 = u & 1;
        const int gw = t4 * 4;                // -> padded cols gw+2..gw+5
        float4 v[8];
        if (rok) {
            const float* xp = x + ((size_t)(b * CIN + sh8 * 8) * HH + gh) * WW + gw;
            #pragma unroll
            for (int i = 0; i < 8; ++i) v[i] = *(const float4*)(xp + (size_t)i * HW);
        } else {
            #pragma unroll
            for (int i = 0; i < 8; ++i) v[i] = make_float4(0.f, 0.f, 0.f, 0.f);
        }
        #pragma unroll
        for (int p = 0; p < 4; ++p) {
            const int pcol = gw + 2 + p;
            const float* f = (const float*)&v[0];
            int4 pk;
            pk.x = (int)((unsigned)f2bf(((const float*)&v[0])[p]) | ((unsigned)f2bf(((const float*)&v[1])[p]) << 16));
            pk.y = (int)((unsigned)f2bf(((const float*)&v[2])[p]) | ((unsigned)f2bf(((const float*)&v[3])[p]) << 16));
            pk.z = (int)((unsigned)f2bf(((const float*)&v[4])[p]) | ((unsigned)f2bf(((const float*)&v[5])[p]) << 16));
            pk.w = (int)((unsigned)f2bf(((const float*)&v[6])[p]) | ((unsigned)f2bf(((const float*)&v[7])[p]) << 16));
            const int unit = pcol * 2 + (sh8 ^ ((pcol >> 2) & 1));
            *(int4*)(dst + (size_t)unit * 8) = pk;
            (void)f;
        }
    } else if (u == 112) {                    // halo cols 0,1,226,227 (both halves)
        const int4 z = make_int4(0, 0, 0, 0);
        #pragma unroll
        for (int i = 0; i < 4; ++i) {
            const int pcol = (i < 2) ? i : 224 + i;
            *(int4*)(dst + (size_t)(pcol * 2 + 0) * 8) = z;
            *(int4*)(dst + (size_t)(pcol * 2 + 1) * 8) = z;
        }
    }
}

// ---- main: block = (4 output rows, batch), 7 waves of 32 px x 32 branches --
__global__ __launch_bounds__(448, 2)
void semiconv_main(const short* __restrict__ xT,
                   const short* __restrict__ wfrag,
                   const float* __restrict__ bc,
                   float* __restrict__ out) {
    __shared__ short tile[8 * UNITS * 8];     // 58368 B: slab rows h..h+7

    const int bidx = blockIdx.x;              // 0..55
    const int b = blockIdx.y;
    const int band = (bidx & 7) * 7 + (bidx >> 3);   // XCD-contiguous bands
    const int h = band * 4;
    const int tid = threadIdx.x;
    const int wave = tid >> 6;
    const int lane = tid & 63;

    // 8 padded rows h..h+7: ONE contiguous span = 3648 x 16B chunks
    const short* src0 = xT + ((size_t)b * PH + h) * (UNITS * 8);
    #pragma unroll
    for (int i = 0; i < 8; ++i) {
        __builtin_amdgcn_global_load_lds(
            (const __attribute__((address_space(1))) void*)(src0 + (size_t)(tid + i * 448) * 8),
            (__attribute__((address_space(3))) void*)(tile + (wave * 64 + i * 448) * 8),
            16, 0, 0);
    }
    if (tid < 64) {                            // tail chunks 3584..3647
        const int chunk = 3584 + tid;
        *(int4*)(tile + chunk * 8) = *(const int4*)(src0 + (size_t)chunk * 8);
    }
    __syncthreads();

    const int l31 = lane & 31;                // px within wave tile; also branch
    const int chalf = lane >> 5;              // channel half for A; px quad for D
    const int wbase = wave * 32;

    f32x16 acc[4] = {};                       // one 32x32 tile per output row
    const short8* wfv = (const short8*)wfrag;

    #pragma unroll
    for (int s = 0; s < 25; ++s) {
        const int kh = s / 5, kw = s % 5;
        const short8 bfr = wfv[s * 64 + lane];
        const int px = wbase + l31 + kw;
        const int ubase = px * 2 + (chalf ^ ((px >> 2) & 1));
        #pragma unroll
        for (int r = 0; r < 4; ++r) {
            const short8 a = *(const short8*)&tile[(size_t)((r + kh) * UNITS + ubase) * 8];
            acc[r] = __builtin_amdgcn_mfma_f32_32x32x16_bf16(a, bfr, acc[r], 0, 0, 0);
        }
    }

    // ---- epilogue: D col = branch = l31; row(px) = (reg&3)+8*(reg>>2)+4*chalf
    const float bias = bc[l31];
    #pragma unroll
    for (int r = 0; r < 4; ++r) {
        const int hrow = h + r;
        float* orow = out + (((size_t)b * NBR + l31) * HH + hrow) * WW;
        #pragma unroll
        for (int q = 0; q < 4; ++q) {
            const int w0c = wbase + q * 8 + chalf * 4;
            float4 o;
            o.x = __builtin_amdgcn_rcpf(1.0f + __expf(-(acc[r][q * 4 + 0] + bias)));
            o.y = __builtin_amdgcn_rcpf(1.0f + __expf(-(acc[r][q * 4 + 1] + bias)));
            o.z = __builtin_amdgcn_rcpf(1.0f + __expf(-(acc[r][q * 4 + 2] + bias)));
            o.w = __builtin_amdgcn_rcpf(1.0f + __expf(-(acc[r][q * 4 + 3] + bias)));
            *(float4*)(orow + w0c) = o;
        }
    }
}

extern "C" void kernel_launch(void* const* d_in, const int* in_sizes, int n_in,
                              void* d_out, int out_size, void* d_ws, size_t ws_size,
                              hipStream_t stream) {
    const float* x  = (const float*)d_in[0];
    const float* Wc = (const float*)d_in[1];
    const float* bc = (const float*)d_in[2];
    float* out = (float*)d_out;

    short* wfrag = (short*)d_ws;                         // 26,624 B
    short* xT    = (short*)((char*)d_ws + 32768);        // 16*228*456*16 B = 26.6 MB

    prep_wfrag32<<<26, 64, 0, stream>>>(Wc, wfrag);
    transpose_x<<<dim3(57, 16), 512, 0, stream>>>(x, xT);
    semiconv_main<<<dim3(56, 16), 448, 0, stream>>>(xT, wfrag, bc, out);
}